// Round 1
// baseline (689.829 us; speedup 1.0000x reference)
//
#include <hip/hip_runtime.h>
#include <math.h>

#define IN_DIM 512
#define HID    256
#define ZD     64

// ---------------- CSR build ----------------

__global__ void k_zero_int(int* p, int n) {
    int i = blockIdx.x * blockDim.x + threadIdx.x;
    if (i < n) p[i] = 0;
}

__global__ void k_count(const int* __restrict__ src, int* __restrict__ deg, int E) {
    int e = blockIdx.x * blockDim.x + threadIdx.x;
    if (e < E) atomicAdd(&deg[src[e]], 1);
}

// single block, 256 threads, N % 256 == 0
__global__ __launch_bounds__(256) void k_scan(const int* __restrict__ deg,
                                              int* __restrict__ rp,
                                              int* __restrict__ nxt, int N) {
    __shared__ int sums[256];
    int t = threadIdx.x;
    int chunk = N / 256;
    int base = t * chunk;
    int run = 0;
    for (int i = 0; i < chunk; ++i) run += deg[base + i];
    sums[t] = run;
    __syncthreads();
    for (int off = 1; off < 256; off <<= 1) {
        int u = (t >= off) ? sums[t - off] : 0;
        __syncthreads();
        sums[t] += u;
        __syncthreads();
    }
    int excl = (t == 0) ? 0 : sums[t - 1];
    int run2 = excl;
    for (int i = 0; i < chunk; ++i) {
        rp[base + i]  = run2;
        nxt[base + i] = run2;
        run2 += deg[base + i];
    }
    if (t == 255) rp[N] = run2;
}

__global__ void k_scatter(const int* __restrict__ src, const int* __restrict__ dst,
                          const float* __restrict__ w, int* __restrict__ nxt,
                          int* __restrict__ col, float* __restrict__ wv, int E) {
    int e = blockIdx.x * blockDim.x + threadIdx.x;
    if (e < E) {
        int pos = atomicAdd(&nxt[src[e]], 1);
        col[pos] = dst[e];
        wv[pos]  = w[e];
    }
}

// ---------------- GEMM1: h0 = x @ W1 + b1 ----------------
// 64x64 tile, 16 k-chunk, 256 threads, 4x4 micro-tile
__global__ __launch_bounds__(256) void k_gemm1(const float* __restrict__ x,
                                               const float* __restrict__ W1,
                                               const float* __restrict__ b1,
                                               float* __restrict__ h0) {
    __shared__ float As[16][68];   // [k][m], padded
    __shared__ float Bs[16][68];   // [k][n], padded
    int tx = threadIdx.x, ty = threadIdx.y;
    int t = ty * 16 + tx;
    int rowBase = blockIdx.y * 64, colBase = blockIdx.x * 64;
    float acc[4][4] = {};
    int kk_l = t & 15, m0 = t >> 4;
    int c_l = t & 63, k_l = t >> 6;
    for (int k0 = 0; k0 < IN_DIM; k0 += 16) {
        #pragma unroll
        for (int p = 0; p < 4; ++p) {
            int m = m0 + p * 16;
            As[kk_l][m] = x[(size_t)(rowBase + m) * IN_DIM + k0 + kk_l];
        }
        #pragma unroll
        for (int p = 0; p < 4; ++p) {
            int kk = k_l + p * 4;
            Bs[kk][c_l] = W1[(size_t)(k0 + kk) * HID + colBase + c_l];
        }
        __syncthreads();
        #pragma unroll
        for (int kk = 0; kk < 16; ++kk) {
            float4 a4 = *(const float4*)&As[kk][ty * 4];
            float4 b4 = *(const float4*)&Bs[kk][tx * 4];
            float a[4] = {a4.x, a4.y, a4.z, a4.w};
            float b[4] = {b4.x, b4.y, b4.z, b4.w};
            #pragma unroll
            for (int r = 0; r < 4; ++r)
                #pragma unroll
                for (int c = 0; c < 4; ++c)
                    acc[r][c] += a[r] * b[c];
        }
        __syncthreads();
    }
    float4 bias = *(const float4*)&b1[colBase + tx * 4];
    float bb[4] = {bias.x, bias.y, bias.z, bias.w};
    #pragma unroll
    for (int r = 0; r < 4; ++r) {
        float4 o;
        o.x = acc[r][0] + bb[0];
        o.y = acc[r][1] + bb[1];
        o.z = acc[r][2] + bb[2];
        o.w = acc[r][3] + bb[3];
        *(float4*)&h0[(size_t)(rowBase + ty * 4 + r) * HID + colBase + tx * 4] = o;
    }
}

// ---------------- SpMM layer1 + tanh: h = tanh(A @ h0) ----------------
__global__ __launch_bounds__(256) void k_spmm_tanh(const int* __restrict__ rp,
                                                   const int* __restrict__ col,
                                                   const float* __restrict__ wv,
                                                   const float* __restrict__ h0,
                                                   float* __restrict__ h) {
    __shared__ int scol[256];
    __shared__ float sw[256];
    int i = blockIdx.x, t = threadIdx.x;
    int s = rp[i], e = rp[i + 1];
    float acc = 0.f;
    for (int cs = s; cs < e; cs += 256) {
        int n = min(256, e - cs);
        __syncthreads();
        if (t < n) { scol[t] = col[cs + t]; sw[t] = wv[cs + t]; }
        __syncthreads();
        #pragma unroll 4
        for (int p = 0; p < n; ++p)
            acc += sw[p] * h0[(size_t)scol[p] * HID + t];
    }
    h[(size_t)i * HID + t] = tanhf(acc);
}

// ---------------- heads: hm = h@Wmu + bmu, hl = h@Wls + bls ----------------
// 16 rows per block, 256 threads = 64 cols x 4 row-groups
__global__ __launch_bounds__(256) void k_heads(const float* __restrict__ h,
                                               const float* __restrict__ Wmu,
                                               const float* __restrict__ bmu,
                                               const float* __restrict__ Wls,
                                               const float* __restrict__ bls,
                                               float* __restrict__ hm,
                                               float* __restrict__ hl) {
    __shared__ float ht[16][HID + 1];
    int t = threadIdx.x;
    int rowBase = blockIdx.x * 16;
    #pragma unroll
    for (int p = 0; p < 16; ++p)
        ht[p][t] = h[(size_t)(rowBase + p) * HID + t];
    __syncthreads();
    int c = t & 63, rg = t >> 6;
    float amu[4] = {}, als[4] = {};
    #pragma unroll 4
    for (int k = 0; k < HID; ++k) {
        float wm = Wmu[k * ZD + c];
        float wl = Wls[k * ZD + c];
        #pragma unroll
        for (int r = 0; r < 4; ++r) {
            float hv = ht[rg * 4 + r][k];
            amu[r] += hv * wm;
            als[r] += hv * wl;
        }
    }
    float bm = bmu[c], bl = bls[c];
    #pragma unroll
    for (int r = 0; r < 4; ++r) {
        int row = rowBase + rg * 4 + r;
        hm[(size_t)row * ZD + c] = amu[r] + bm;
        hl[(size_t)row * ZD + c] = als[r] + bl;
    }
}

// ---------------- SpMM heads + reparameterize ----------------
__global__ __launch_bounds__(64) void k_spmm_heads(const int* __restrict__ rp,
                                                   const int* __restrict__ col,
                                                   const float* __restrict__ wv,
                                                   const float* __restrict__ hm,
                                                   const float* __restrict__ hl,
                                                   const float* __restrict__ eps,
                                                   float* __restrict__ mu,
                                                   float* __restrict__ ls,
                                                   float* __restrict__ z) {
    __shared__ int scol[64];
    __shared__ float sw[64];
    int i = blockIdx.x, t = threadIdx.x;
    int s = rp[i], e = rp[i + 1];
    float amu = 0.f, als = 0.f;
    for (int cs = s; cs < e; cs += 64) {
        int n = min(64, e - cs);
        __syncthreads();
        if (t < n) { scol[t] = col[cs + t]; sw[t] = wv[cs + t]; }
        __syncthreads();
        #pragma unroll 4
        for (int p = 0; p < n; ++p) {
            size_t off = (size_t)scol[p] * ZD + t;
            float w = sw[p];
            amu += w * hm[off];
            als += w * hl[off];
        }
    }
    size_t o = (size_t)i * ZD + t;
    mu[o] = amu;
    ls[o] = als;
    z[o]  = amu + eps[o] * expf(als);
}

// ---------------- decoder: adj_logits = z @ z^T ----------------
// 64x64 tile, K=64 single pass, 256 threads, 4x4 micro-tile, float4 over k
__global__ __launch_bounds__(256) void k_zzt(const float* __restrict__ z,
                                             float* __restrict__ out, int N) {
    __shared__ float Az[64][68];
    __shared__ float Bz[64][68];
    int tx = threadIdx.x, ty = threadIdx.y;
    int t = ty * 16 + tx;
    int rowBase = blockIdx.y * 64, colBase = blockIdx.x * 64;
    int k4 = (t & 15) * 4, r0 = t >> 4;
    #pragma unroll
    for (int p = 0; p < 4; ++p) {
        int r = r0 + p * 16;
        *(float4*)&Az[r][k4] = *(const float4*)&z[(size_t)(rowBase + r) * ZD + k4];
        *(float4*)&Bz[r][k4] = *(const float4*)&z[(size_t)(colBase + r) * ZD + k4];
    }
    __syncthreads();
    float acc[4][4] = {};
    #pragma unroll
    for (int kk = 0; kk < 16; ++kk) {
        float4 a4[4], b4[4];
        #pragma unroll
        for (int r = 0; r < 4; ++r) a4[r] = *(const float4*)&Az[ty * 4 + r][kk * 4];
        #pragma unroll
        for (int c = 0; c < 4; ++c) b4[c] = *(const float4*)&Bz[tx * 4 + c][kk * 4];
        #pragma unroll
        for (int r = 0; r < 4; ++r)
            #pragma unroll
            for (int c = 0; c < 4; ++c)
                acc[r][c] += a4[r].x * b4[c].x + a4[r].y * b4[c].y +
                             a4[r].z * b4[c].z + a4[r].w * b4[c].w;
    }
    #pragma unroll
    for (int r = 0; r < 4; ++r) {
        float4 o = make_float4(acc[r][0], acc[r][1], acc[r][2], acc[r][3]);
        *(float4*)&out[(size_t)(rowBase + ty * 4 + r) * N + colBase + tx * 4] = o;
    }
}

// ---------------- launch ----------------

extern "C" void kernel_launch(void* const* d_in, const int* in_sizes, int n_in,
                              void* d_out, int out_size, void* d_ws, size_t ws_size,
                              hipStream_t stream) {
    const float* x    = (const float*)d_in[0];
    const int*   esrc = (const int*)d_in[1];
    const int*   edst = (const int*)d_in[2];
    const float* ew   = (const float*)d_in[3];
    const float* eps  = (const float*)d_in[4];
    const float* W1   = (const float*)d_in[5];
    const float* b1   = (const float*)d_in[6];
    const float* Wmu  = (const float*)d_in[7];
    const float* bmu  = (const float*)d_in[8];
    const float* Wls  = (const float*)d_in[9];
    const float* bls  = (const float*)d_in[10];
    int N = in_sizes[0] / IN_DIM;
    int E = in_sizes[1];

    // workspace layout (floats then ints), ~23 MB total
    float* h0 = (float*)d_ws;
    float* h  = h0 + (size_t)N * HID;
    float* hm = h  + (size_t)N * HID;
    float* hl = hm + (size_t)N * ZD;
    int* rp   = (int*)(hl + (size_t)N * ZD);
    int* deg  = rp + (N + 1);
    int* nxt  = deg + N;
    int* col  = nxt + N;
    float* wv = (float*)(col + E);

    float* out_z   = (float*)d_out;
    float* out_adj = out_z + (size_t)N * ZD;
    float* out_mu  = out_adj + (size_t)N * N;
    float* out_ls  = out_mu + (size_t)N * ZD;

    // CSR build
    k_zero_int<<<(N + 255) / 256, 256, 0, stream>>>(deg, N);
    k_count<<<(E + 255) / 256, 256, 0, stream>>>(esrc, deg, E);
    k_scan<<<1, 256, 0, stream>>>(deg, rp, nxt, N);
    k_scatter<<<(E + 255) / 256, 256, 0, stream>>>(esrc, edst, ew, nxt, col, wv, E);

    // dense layer 1
    dim3 b16(16, 16);
    dim3 g1(HID / 64, N / 64);
    k_gemm1<<<g1, b16, 0, stream>>>(x, W1, b1, h0);

    // spmm + tanh
    k_spmm_tanh<<<N, 256, 0, stream>>>(rp, col, wv, h0, h);

    // heads
    k_heads<<<N / 16, 256, 0, stream>>>(h, Wmu, bmu, Wls, bls, hm, hl);

    // spmm heads + reparameterize
    k_spmm_heads<<<N, 64, 0, stream>>>(rp, col, wv, hm, hl, eps, out_mu, out_ls, out_z);

    // decoder z @ z^T
    dim3 g2(N / 64, N / 64);
    k_zzt<<<g2, b16, 0, stream>>>(out_z, out_adj, N);
}

// Round 2
// 461.013 us; speedup vs baseline: 1.4963x; 1.4963x over previous
//
#include <hip/hip_runtime.h>
#include <math.h>

#define IN_DIM 512
#define HID    256
#define ZD     64

typedef short bf16x8 __attribute__((ext_vector_type(8)));
typedef float f32x4  __attribute__((ext_vector_type(4)));

// ---------------- CSR build ----------------

__global__ void k_zero_int(int* p, int n) {
    int i = blockIdx.x * blockDim.x + threadIdx.x;
    if (i < n) p[i] = 0;
}

__global__ void k_count(const int* __restrict__ src, int* __restrict__ deg, int E) {
    int e = blockIdx.x * blockDim.x + threadIdx.x;
    if (e < E) atomicAdd(&deg[src[e]], 1);
}

// single block, 256 threads, N % 256 == 0
__global__ __launch_bounds__(256) void k_scan(const int* __restrict__ deg,
                                              int* __restrict__ rp,
                                              int* __restrict__ nxt, int N) {
    __shared__ int sums[256];
    int t = threadIdx.x;
    int chunk = N / 256;
    int base = t * chunk;
    int run = 0;
    for (int i = 0; i < chunk; ++i) run += deg[base + i];
    sums[t] = run;
    __syncthreads();
    for (int off = 1; off < 256; off <<= 1) {
        int u = (t >= off) ? sums[t - off] : 0;
        __syncthreads();
        sums[t] += u;
        __syncthreads();
    }
    int excl = (t == 0) ? 0 : sums[t - 1];
    int run2 = excl;
    for (int i = 0; i < chunk; ++i) {
        rp[base + i]  = run2;
        nxt[base + i] = run2;
        run2 += deg[base + i];
    }
    if (t == 255) rp[N] = run2;
}

__global__ void k_scatter(const int* __restrict__ src, const int* __restrict__ dst,
                          const float* __restrict__ w, int* __restrict__ nxt,
                          int* __restrict__ col, float* __restrict__ wv, int E) {
    int e = blockIdx.x * blockDim.x + threadIdx.x;
    if (e < E) {
        int pos = atomicAdd(&nxt[src[e]], 1);
        col[pos] = dst[e];
        wv[pos]  = w[e];
    }
}

// ---------------- GEMM1: h0 = x @ W1 + b1 ----------------
// 64x64 tile, 16 k-chunk, 256 threads, 4x4 micro-tile
__global__ __launch_bounds__(256) void k_gemm1(const float* __restrict__ x,
                                               const float* __restrict__ W1,
                                               const float* __restrict__ b1,
                                               float* __restrict__ h0) {
    __shared__ float As[16][68];   // [k][m], padded
    __shared__ float Bs[16][68];   // [k][n], padded
    int tx = threadIdx.x, ty = threadIdx.y;
    int t = ty * 16 + tx;
    int rowBase = blockIdx.y * 64, colBase = blockIdx.x * 64;
    float acc[4][4] = {};
    int kk_l = t & 15, m0 = t >> 4;
    int c_l = t & 63, k_l = t >> 6;
    for (int k0 = 0; k0 < IN_DIM; k0 += 16) {
        #pragma unroll
        for (int p = 0; p < 4; ++p) {
            int m = m0 + p * 16;
            As[kk_l][m] = x[(size_t)(rowBase + m) * IN_DIM + k0 + kk_l];
        }
        #pragma unroll
        for (int p = 0; p < 4; ++p) {
            int kk = k_l + p * 4;
            Bs[kk][c_l] = W1[(size_t)(k0 + kk) * HID + colBase + c_l];
        }
        __syncthreads();
        #pragma unroll
        for (int kk = 0; kk < 16; ++kk) {
            float4 a4 = *(const float4*)&As[kk][ty * 4];
            float4 b4 = *(const float4*)&Bs[kk][tx * 4];
            float a[4] = {a4.x, a4.y, a4.z, a4.w};
            float b[4] = {b4.x, b4.y, b4.z, b4.w};
            #pragma unroll
            for (int r = 0; r < 4; ++r)
                #pragma unroll
                for (int c = 0; c < 4; ++c)
                    acc[r][c] += a[r] * b[c];
        }
        __syncthreads();
    }
    float4 bias = *(const float4*)&b1[colBase + tx * 4];
    float bb[4] = {bias.x, bias.y, bias.z, bias.w};
    #pragma unroll
    for (int r = 0; r < 4; ++r) {
        float4 o;
        o.x = acc[r][0] + bb[0];
        o.y = acc[r][1] + bb[1];
        o.z = acc[r][2] + bb[2];
        o.w = acc[r][3] + bb[3];
        *(float4*)&h0[(size_t)(rowBase + ty * 4 + r) * HID + colBase + tx * 4] = o;
    }
}

// ---------------- SpMM layer1 + tanh: h = tanh(A @ h0) ----------------
__global__ __launch_bounds__(256) void k_spmm_tanh(const int* __restrict__ rp,
                                                   const int* __restrict__ col,
                                                   const float* __restrict__ wv,
                                                   const float* __restrict__ h0,
                                                   float* __restrict__ h) {
    __shared__ int scol[256];
    __shared__ float sw[256];
    int i = blockIdx.x, t = threadIdx.x;
    int s = rp[i], e = rp[i + 1];
    float acc = 0.f;
    for (int cs = s; cs < e; cs += 256) {
        int n = min(256, e - cs);
        __syncthreads();
        if (t < n) { scol[t] = col[cs + t]; sw[t] = wv[cs + t]; }
        __syncthreads();
        #pragma unroll 4
        for (int p = 0; p < n; ++p)
            acc += sw[p] * h0[(size_t)scol[p] * HID + t];
    }
    h[(size_t)i * HID + t] = tanhf(acc);
}

// ---------------- heads: hm = h@Wmu + bmu, hl = h@Wls + bls ----------------
__global__ __launch_bounds__(256) void k_heads(const float* __restrict__ h,
                                               const float* __restrict__ Wmu,
                                               const float* __restrict__ bmu,
                                               const float* __restrict__ Wls,
                                               const float* __restrict__ bls,
                                               float* __restrict__ hm,
                                               float* __restrict__ hl) {
    __shared__ float ht[16][HID + 1];
    int t = threadIdx.x;
    int rowBase = blockIdx.x * 16;
    #pragma unroll
    for (int p = 0; p < 16; ++p)
        ht[p][t] = h[(size_t)(rowBase + p) * HID + t];
    __syncthreads();
    int c = t & 63, rg = t >> 6;
    float amu[4] = {}, als[4] = {};
    #pragma unroll 4
    for (int k = 0; k < HID; ++k) {
        float wm = Wmu[k * ZD + c];
        float wl = Wls[k * ZD + c];
        #pragma unroll
        for (int r = 0; r < 4; ++r) {
            float hv = ht[rg * 4 + r][k];
            amu[r] += hv * wm;
            als[r] += hv * wl;
        }
    }
    float bm = bmu[c], bl = bls[c];
    #pragma unroll
    for (int r = 0; r < 4; ++r) {
        int row = rowBase + rg * 4 + r;
        hm[(size_t)row * ZD + c] = amu[r] + bm;
        hl[(size_t)row * ZD + c] = als[r] + bl;
    }
}

// ---------------- SpMM heads + reparameterize ----------------
__global__ __launch_bounds__(64) void k_spmm_heads(const int* __restrict__ rp,
                                                   const int* __restrict__ col,
                                                   const float* __restrict__ wv,
                                                   const float* __restrict__ hm,
                                                   const float* __restrict__ hl,
                                                   const float* __restrict__ eps,
                                                   float* __restrict__ mu,
                                                   float* __restrict__ ls,
                                                   float* __restrict__ z) {
    __shared__ int scol[64];
    __shared__ float sw[64];
    int i = blockIdx.x, t = threadIdx.x;
    int s = rp[i], e = rp[i + 1];
    float amu = 0.f, als = 0.f;
    for (int cs = s; cs < e; cs += 64) {
        int n = min(64, e - cs);
        __syncthreads();
        if (t < n) { scol[t] = col[cs + t]; sw[t] = wv[cs + t]; }
        __syncthreads();
        #pragma unroll 4
        for (int p = 0; p < n; ++p) {
            size_t off = (size_t)scol[p] * ZD + t;
            float w = sw[p];
            amu += w * hm[off];
            als += w * hl[off];
        }
    }
    size_t o = (size_t)i * ZD + t;
    mu[o] = amu;
    ls[o] = als;
    z[o]  = amu + eps[o] * expf(als);
}

// ---------------- z fp32 -> bf16 (RNE) ----------------
__global__ void k_cvt_bf16(const float* __restrict__ z, unsigned short* __restrict__ zb, int n4) {
    int i = blockIdx.x * blockDim.x + threadIdx.x;
    if (i < n4) {
        float4 v = *(const float4*)&z[i * 4];
        float vv[4] = {v.x, v.y, v.z, v.w};
        ushort4 o;
        unsigned short* op = (unsigned short*)&o;
        #pragma unroll
        for (int j = 0; j < 4; ++j) {
            unsigned int b = __float_as_uint(vv[j]);
            b += 0x7FFFu + ((b >> 16) & 1u);   // round-to-nearest-even
            op[j] = (unsigned short)(b >> 16);
        }
        *(ushort4*)&zb[i * 4] = o;
    }
}

// ---------------- decoder: adj_logits = z @ z^T via bf16 MFMA ----------------
// block = 256 threads (4 waves as 2x2), block tile 128x128, wave tile 64x64
// K = 64 = 2 mfma_16x16x32 per output tile. No LDS: z_bf is 1 MB, L2-resident.
// A-frag layout (verified m120): lane holds A[m=lane&15][k=(lane>>4)*8 + j], j=0..7
// For z*z^T the B fragment gather is identical (B[k][n] = z[n][k]).
__global__ __launch_bounds__(256) void k_zzt_mfma(const unsigned short* __restrict__ zb,
                                                  float* __restrict__ out, int N) {
    int lane = threadIdx.x & 63;
    int w    = threadIdx.x >> 6;         // 0..3
    int waveRow = blockIdx.y * 128 + (w >> 1) * 64;
    int waveCol = blockIdx.x * 128 + (w & 1) * 64;
    int m    = lane & 15;
    int quad = lane >> 4;
    int kofs = quad * 8;

    bf16x8 a[4][2], b[4][2];
    #pragma unroll
    for (int rg = 0; rg < 4; ++rg) {
        const unsigned short* pr = zb + (size_t)(waveRow + rg * 16 + m) * ZD + kofs;
        const unsigned short* pc = zb + (size_t)(waveCol + rg * 16 + m) * ZD + kofs;
        a[rg][0] = *(const bf16x8*)pr;
        a[rg][1] = *(const bf16x8*)(pr + 32);
        b[rg][0] = *(const bf16x8*)pc;
        b[rg][1] = *(const bf16x8*)(pc + 32);
    }

    f32x4 acc[4][4] = {};
    #pragma unroll
    for (int rg = 0; rg < 4; ++rg)
        #pragma unroll
        for (int cg = 0; cg < 4; ++cg) {
            acc[rg][cg] = __builtin_amdgcn_mfma_f32_16x16x32_bf16(a[rg][0], b[cg][0], acc[rg][cg], 0, 0, 0);
            acc[rg][cg] = __builtin_amdgcn_mfma_f32_16x16x32_bf16(a[rg][1], b[cg][1], acc[rg][cg], 0, 0, 0);
        }

    // C/D layout (verified m89/m91): col = lane&15, row = (lane>>4)*4 + reg
    #pragma unroll
    for (int rg = 0; rg < 4; ++rg) {
        int row0 = waveRow + rg * 16 + quad * 4;
        #pragma unroll
        for (int cg = 0; cg < 4; ++cg) {
            int c = waveCol + cg * 16 + m;
            #pragma unroll
            for (int r = 0; r < 4; ++r)
                out[(size_t)(row0 + r) * N + c] = acc[rg][cg][r];
        }
    }
}

// ---------------- launch ----------------

extern "C" void kernel_launch(void* const* d_in, const int* in_sizes, int n_in,
                              void* d_out, int out_size, void* d_ws, size_t ws_size,
                              hipStream_t stream) {
    const float* x    = (const float*)d_in[0];
    const int*   esrc = (const int*)d_in[1];
    const int*   edst = (const int*)d_in[2];
    const float* ew   = (const float*)d_in[3];
    const float* eps  = (const float*)d_in[4];
    const float* W1   = (const float*)d_in[5];
    const float* b1   = (const float*)d_in[6];
    const float* Wmu  = (const float*)d_in[7];
    const float* bmu  = (const float*)d_in[8];
    const float* Wls  = (const float*)d_in[9];
    const float* bls  = (const float*)d_in[10];
    int N = in_sizes[0] / IN_DIM;
    int E = in_sizes[1];

    // workspace layout
    float* h0 = (float*)d_ws;
    float* h  = h0 + (size_t)N * HID;
    float* hm = h  + (size_t)N * HID;
    float* hl = hm + (size_t)N * ZD;
    int* rp   = (int*)(hl + (size_t)N * ZD);
    int* deg  = rp + (N + 1);
    int* nxt  = deg + N;
    int* col  = nxt + N;
    float* wv = (float*)(col + E);
    unsigned short* zb = (unsigned short*)(wv + E);   // N*ZD bf16 = 1 MB

    float* out_z   = (float*)d_out;
    float* out_adj = out_z + (size_t)N * ZD;
    float* out_mu  = out_adj + (size_t)N * N;
    float* out_ls  = out_mu + (size_t)N * ZD;

    // CSR build
    k_zero_int<<<(N + 255) / 256, 256, 0, stream>>>(deg, N);
    k_count<<<(E + 255) / 256, 256, 0, stream>>>(esrc, deg, E);
    k_scan<<<1, 256, 0, stream>>>(deg, rp, nxt, N);
    k_scatter<<<(E + 255) / 256, 256, 0, stream>>>(esrc, edst, ew, nxt, col, wv, E);

    // dense layer 1
    dim3 b16(16, 16);
    dim3 g1(HID / 64, N / 64);
    k_gemm1<<<g1, b16, 0, stream>>>(x, W1, b1, h0);

    // spmm + tanh
    k_spmm_tanh<<<N, 256, 0, stream>>>(rp, col, wv, h0, h);

    // heads
    k_heads<<<N / 16, 256, 0, stream>>>(h, Wmu, bmu, Wls, bls, hm, hl);

    // spmm heads + reparameterize
    k_spmm_heads<<<N, 64, 0, stream>>>(rp, col, wv, hm, hl, eps, out_mu, out_ls, out_z);

    // z -> bf16
    k_cvt_bf16<<<(N * ZD / 4 + 255) / 256, 256, 0, stream>>>(out_z, zb, N * ZD / 4);

    // decoder z @ z^T (bf16 MFMA, fp32 accum)
    dim3 g2(N / 128, N / 128);
    k_zzt_mfma<<<g2, 256, 0, stream>>>(zb, out_adj, N);
}